// Round 16
// baseline (175.220 us; speedup 1.0000x reference)
//
#include <hip/hip_runtime.h>
#include <hip/hip_bf16.h>
#include <math.h>

#define B_DIM 8
#define C_DIM 32
#define N_DIM 4096
#define KSPLIT 2
#define KSL (N_DIM / KSPLIT)   // 2048 k per block
#define NCH (KSL / 32)         // 64 chunks

typedef short bf16x8 __attribute__((ext_vector_type(8)));   // 8 bf16 = 4 VGPRs
typedef float f32x4 __attribute__((ext_vector_type(4)));
typedef unsigned int uint4v __attribute__((ext_vector_type(4)));
typedef unsigned short ushort8 __attribute__((ext_vector_type(8)));

__device__ __forceinline__ ushort f2bf_rne(float f) {
  unsigned u = __float_as_uint(f);
  u += 0x7FFF + ((u >> 16) & 1);
  return (ushort)(u >> 16);
}

// async global->LDS DMA, 16 B/lane. lds dest must be wave-uniform; lane i
// lands at lds + i*16 (m97/m104 semantics).
__device__ __forceinline__ void gl_lds16(const void* g, void* l) {
  __builtin_amdgcn_global_load_lds(
      (const __attribute__((address_space(1))) void*)g,
      (__attribute__((address_space(3))) void*)l, 16, 0, 0);
}

// Prep A: E[b,n] = exp(mean_c x[b,c,n]); hot loop uses the exact identity
// 2*sigmoid(-|ck-cm|) = min(Ek,Em) / (0.5*(Ek+Em)).
__global__ __launch_bounds__(256) void prep_e(const float* __restrict__ x,
                                              float* __restrict__ E) {
  int idx = blockIdx.x * 256 + threadIdx.x;   // 0 .. B*N-1
  int b = idx >> 12;
  int n = idx & (N_DIM - 1);
  const float* p = x + (size_t)b * C_DIM * N_DIM + n;
  float s = 0.f;
#pragma unroll
  for (int c = 0; c < C_DIM; ++c) s += p[(size_t)c * N_DIM];
  E[idx] = __builtin_amdgcn_exp2f(s * (1.44269504f / C_DIM));
}

// Prep B: feabT tiled bf16: feabT[((b*128 + n/32)*32 + c)*32 + n%32]
__global__ __launch_bounds__(256) void prep_feab(const float* __restrict__ x,
                                                 ushort* __restrict__ feabT) {
  int idx = blockIdx.x * 256 + threadIdx.x;   // 0 .. 8*32*256-1
  int g = idx & 255;           // n-group of 16
  int c = (idx >> 8) & 31;
  int b = idx >> 13;
  int n0 = g * 16;
  const float* p = x + ((size_t)(b * C_DIM + c)) * N_DIM + n0;
  ushort* q = feabT + ((size_t)(b * (N_DIM / 32) + (n0 >> 5)) * C_DIM + c) * 32 + (n0 & 31);
  ushort8 v0, v1;
#pragma unroll
  for (int j = 0; j < 8; ++j) v0[j] = f2bf_rne(p[j]);
#pragma unroll
  for (int j = 0; j < 8; ++j) v1[j] = f2bf_rne(p[8 + j]);
  *(ushort8*)q = v0;
  *(ushort8*)(q + 8) = v1;
}

// Stage 1: barrier-free async pipeline. Block = 8 waves = 8 batches, 16 cols,
// K-half. Per chunk each wave: (a) adj+E for ch+1 into register dbuf, issued
// FIRST; (b) fea tile ch+1 via global_load_lds into its private LDS landing
// zone (double-buffered; no VGPR held -> the compiler cannot collapse the
// pipeline; no barrier -> no forced vmcnt(0) drain); (c) ds_read_b128 the
// ch fragments; (d) weight-gen + MFMA using last iteration's adj/E regs.
// All vmcnt waits target ops OLDER than the newly issued DMAs (FIFO-safe).
__global__ __launch_bounds__(512, 4) void gcn_stage1(
    const ushort* __restrict__ feabT, const float* __restrict__ adj,
    const float* __restrict__ E, float* __restrict__ part) {
  __shared__ ushort feabuf[2][B_DIM][1024];   // 32 KB: 2 bufs x 8 waves x 2 KB

  const int tid = threadIdx.x;
  const int lane = tid & 63;
  const int b = tid >> 6;           // wave id = batch
  const int quad = lane >> 4;
  const int l15 = lane & 15;
  const int colgrp = blockIdx.x;    // 0..255
  const int kh = blockIdx.y;        // 0..1
  const int col = colgrp * 16 + l15;
  const int ksbase = kh * KSL;

  const float* Eb = E + (size_t)b * N_DIM;
  const float Em = Eb[col];
  const float hEm = 0.5f * Em;
  const float* ekb = Eb + ksbase;
  const ushort* fb = feabT + ((size_t)b * (N_DIM / 32) + (ksbase >> 5)) * (C_DIM * 32);
  const int foff = l15 * 32 + quad * 8;   // per-lane element offset in a tile

  f32x4 acc0 = {0.f, 0.f, 0.f, 0.f};   // channels 0-15
  f32x4 acc1 = {0.f, 0.f, 0.f, 0.f};   // channels 16-31

  float adjv[2][8];   // adj fragment, register dbuf
  float ekv[2][8];    // E k-values, register dbuf

#define ADJ_E_STAGE(ch_, s_)                                                  \
  {                                                                           \
    const int kr = ksbase + (ch_) * 32 + quad * 8;                            \
    _Pragma("unroll")                                                         \
    for (int j = 0; j < 8; ++j)                                               \
      adjv[s_][j] = adj[(size_t)(kr + j) * N_DIM + col];                      \
    *(f32x4*)&ekv[s_][0] = *(const f32x4*)(ekb + (ch_) * 32 + quad * 8);      \
    *(f32x4*)&ekv[s_][4] = *(const f32x4*)(ekb + (ch_) * 32 + quad * 8 + 4);  \
  }

#define FEA_DMA(ch_, s_)                                                      \
  {                                                                           \
    const ushort* t_ = fb + (size_t)(ch_) * (C_DIM * 32) + foff;              \
    gl_lds16(t_, &feabuf[s_][b][0]);                                          \
    gl_lds16(t_ + 512, &feabuf[s_][b][512]);                                  \
  }

  // prologue: regs for chunk 0, DMA for chunk 0
  ADJ_E_STAGE(0, 0)
  FEA_DMA(0, 0)

#pragma unroll 2
  for (int ch = 0; ch < NCH; ++ch) {
    const int s = ch & 1;
    // issue next chunk's reg loads FIRST, then its DMAs (FIFO: any wait for
    // this chunk's data leaves the new DMAs in flight)
    if (ch + 1 < NCH) {
      ADJ_E_STAGE(ch + 1, s ^ 1)
      FEA_DMA(ch + 1, s ^ 1)
    }

    // consume chunk ch: fragments from the LDS landing zone (identity map)
    const bf16x8 fa0 = *(const bf16x8*)&feabuf[s][b][lane * 8];
    const bf16x8 fa1 = *(const bf16x8*)&feabuf[s][b][512 + lane * 8];

    // w = adj * min(Ek,Em) * rcp(0.5*Ek + 0.5*Em)   (== 2*adj*sigmoid(-|d|))
    uint4v wfu;
#pragma unroll
    for (int p = 0; p < 4; ++p) {
      const float e0 = ekv[s][2 * p];
      const float e1 = ekv[s][2 * p + 1];
      const float t0 = fminf(e0, Em);
      const float t1 = fminf(e1, Em);
      const float s0 = fmaf(0.5f, e0, hEm);
      const float s1 = fmaf(0.5f, e1, hEm);
      const float w0 = adjv[s][2 * p] * t0 * __builtin_amdgcn_rcpf(s0);
      const float w1 = adjv[s][2 * p + 1] * t1 * __builtin_amdgcn_rcpf(s1);
      // truncating bf16x2 pack: bytes [w0.b2, w0.b3, w1.b2, w1.b3]
      wfu[p] = __builtin_amdgcn_perm(__float_as_uint(w1), __float_as_uint(w0),
                                     0x07060302u);
    }
    const bf16x8 wf = __builtin_bit_cast(bf16x8, wfu);

    acc0 = __builtin_amdgcn_mfma_f32_16x16x32_bf16(fa0, wf, acc0, 0, 0, 0);
    acc1 = __builtin_amdgcn_mfma_f32_16x16x32_bf16(fa1, wf, acc1, 0, 0, 0);
  }

  // partials: part[kh][b][c][col]   (D layout: col=l15, row=quad*4+r)
  float* pp = part + ((size_t)(kh * B_DIM + b) * C_DIM) * N_DIM;
#pragma unroll
  for (int r = 0; r < 4; ++r) {
    const int c0 = quad * 4 + r;
    pp[(size_t)c0 * N_DIM + col] = acc0[r];
    pp[(size_t)(c0 + 16) * N_DIM + col] = acc1[r];
  }
}

// Epilogue: out = relu(para * (part[0] + part[1]))
__global__ __launch_bounds__(256) void epilogue_kernel(const float* __restrict__ part,
                                                       const float* __restrict__ para,
                                                       float* __restrict__ out) {
  const int t = blockIdx.x * 256 + threadIdx.x;    // float4 groups
  const int m4 = (t & 1023) * 4;
  const int bc = t >> 10;                          // b*32 + c
  const int c = bc & 31;
  const size_t base = (size_t)bc * N_DIM + m4;

  f32x4 s = {0.f, 0.f, 0.f, 0.f};
#pragma unroll
  for (int ks = 0; ks < KSPLIT; ++ks)
    s += *(const f32x4*)(part + (size_t)ks * (B_DIM * C_DIM * N_DIM) + base);

  const f32x4 p = *(const f32x4*)(para + (size_t)c * N_DIM + m4);
  f32x4 o;
#pragma unroll
  for (int i = 0; i < 4; ++i) o[i] = fmaxf(s[i] * p[i], 0.f);
  *(f32x4*)(out + base) = o;
}

extern "C" void kernel_launch(void* const* d_in, const int* in_sizes, int n_in,
                              void* d_out, int out_size, void* d_ws, size_t ws_size,
                              hipStream_t stream) {
  const float* x = (const float*)d_in[0];     // [8,32,64,64]
  const float* para = (const float*)d_in[1];  // [1,32,64,64]
  const float* adj = (const float*)d_in[2];   // [4096,4096]
  float* out = (float*)d_out;

  // ws: part (8 MB) | E (128 KB) | feabT (2 MB)
  float* part = (float*)d_ws;
  float* E = (float*)((char*)d_ws + (size_t)KSPLIT * B_DIM * C_DIM * N_DIM * 4);
  ushort* feabT = (ushort*)(E + (size_t)B_DIM * N_DIM);

  prep_e<<<dim3(B_DIM * N_DIM / 256), dim3(256), 0, stream>>>(x, E);
  prep_feab<<<dim3(B_DIM * C_DIM * (N_DIM / 16) / 256), dim3(256), 0, stream>>>(x, feabT);
  gcn_stage1<<<dim3(N_DIM / 16, KSPLIT), dim3(512), 0, stream>>>(feabT, adj, E, part);
  epilogue_kernel<<<dim3(B_DIM * C_DIM * N_DIM / 4 / 256), dim3(256), 0, stream>>>(part, para, out);
}

// Round 17
// 142.214 us; speedup vs baseline: 1.2321x; 1.2321x over previous
//
#include <hip/hip_runtime.h>
#include <hip/hip_bf16.h>
#include <math.h>

#define B_DIM 8
#define C_DIM 32
#define N_DIM 4096
#define KSL 2048           // k per kh-group
#define NCH (KSL / 32)     // 64 chunks

typedef short bf16x8 __attribute__((ext_vector_type(8)));   // 8 bf16 = 4 VGPRs
typedef float f32x4 __attribute__((ext_vector_type(4)));
typedef unsigned int uint4v __attribute__((ext_vector_type(4)));
typedef unsigned short ushort8 __attribute__((ext_vector_type(8)));

__device__ __forceinline__ ushort f2bf_rne(float f) {
  unsigned u = __float_as_uint(f);
  u += 0x7FFF + ((u >> 16) & 1);
  return (ushort)(u >> 16);
}

// Prep A: E[b,n] = exp(mean_c x[b,c,n]).  Hot loop uses the exact identity
// 2*sigmoid(-|ck-cm|) = 2*min(Ek,Em)/(Ek+Em).
__global__ __launch_bounds__(256) void prep_e(const float* __restrict__ x,
                                              float* __restrict__ E) {
  int idx = blockIdx.x * 256 + threadIdx.x;   // 0 .. B*N-1
  int b = idx >> 12;
  int n = idx & (N_DIM - 1);
  const float* p = x + (size_t)b * C_DIM * N_DIM + n;
  float s = 0.f;
#pragma unroll
  for (int c = 0; c < C_DIM; ++c) s += p[(size_t)c * N_DIM];
  E[idx] = __builtin_amdgcn_exp2f(s * (1.44269504f / C_DIM));
}

// Prep B: feabT tiled bf16: feabT[((b*128 + n/32)*32 + c)*32 + n%32]
__global__ __launch_bounds__(256) void prep_feab(const float* __restrict__ x,
                                                 ushort* __restrict__ feabT) {
  int idx = blockIdx.x * 256 + threadIdx.x;   // 0 .. 8*32*256-1
  int g = idx & 255;           // n-group of 16
  int c = (idx >> 8) & 31;
  int b = idx >> 13;
  int n0 = g * 16;
  const float* p = x + ((size_t)(b * C_DIM + c)) * N_DIM + n0;
  ushort* q = feabT + ((size_t)(b * (N_DIM / 32) + (n0 >> 5)) * C_DIM + c) * 32 + (n0 & 31);
  ushort8 v0, v1;
#pragma unroll
  for (int j = 0; j < 8; ++j) v0[j] = f2bf_rne(p[j]);
#pragma unroll
  for (int j = 0; j < 8; ++j) v1[j] = f2bf_rne(p[8 + j]);
  *(ushort8*)q = v0;
  *(ushort8*)(q + 8) = v1;
}

// Fused: block = 16 waves (1024 thr) = 2 kh-groups x 8 batches; each kh-group
// is EXACTLY the r15 stage1 (8 waves share a cooperatively-staged adj tile in
// its own abuf, depth-2 register staging pipeline, 2 barriers/chunk, adj read
// once chip-wide). After the K loop: kh=1 stashes partials in LDS, one
// barrier, kh=0 adds + para*relu + stores out. No part buffer, no epilogue
// dispatch; ws shrinks 10.25 -> 2.25 MB.
__global__ __launch_bounds__(1024, 4) void gcn_fused(
    const ushort* __restrict__ feabT, const float* __restrict__ adj,
    const float* __restrict__ E, const float* __restrict__ para,
    float* __restrict__ out) {
  __shared__ float abuf[2][32 * 33 + 4];   // ~8.5 KB, row stride 33
  __shared__ float red[B_DIM][512];        // 16 KB reduce buffer

  const int tid = threadIdx.x;
  const int lane = tid & 63;
  const int w = tid >> 6;           // 0..15
  const int b = w & 7;              // batch
  const int kh = w >> 3;            // 0..1 = K-half
  const int quad = lane >> 4;
  const int l15 = lane & 15;
  const int colgrp = blockIdx.x;    // 0..255
  const int col = colgrp * 16 + l15;
  const int ksbase = kh * KSL;

  // staging: each kh-group's 512 threads cover its 32x16 tile, 1 elem each
  const int tg = tid & 511;
  const float* agp = adj + (size_t)(ksbase + (tg >> 4)) * N_DIM + colgrp * 16 + (tg & 15);
  const int swaddr = (tg >> 4) * 33 + (tg & 15);

  const float* Eb = E + (size_t)b * N_DIM;
  const float Em = Eb[col];
  const float* ekb = Eb + ksbase;
  const ushort* fb = feabT + ((size_t)b * (N_DIM / 32) + (ksbase >> 5)) * (C_DIM * 32);

  f32x4 acc0 = {0.f, 0.f, 0.f, 0.f};   // channels 0-15
  f32x4 acc1 = {0.f, 0.f, 0.f, 0.f};   // channels 16-31

  // depth-2 adj staging pipeline (a_nxt = tile ch+1, a_nx2 = tile ch+2)
  float a_nxt = agp[0];
  float a_nx2 = agp[(size_t)32 * N_DIM];
  abuf[kh][swaddr] = 2.0f * a_nxt;   // tile 0 into LDS
  a_nxt = a_nx2;
  __syncthreads();

  for (int ch = 0; ch < NCH; ++ch) {
    // issue tile ch+2's staging load now (~2 chunks of distance to its use)
    if (ch + 2 < NCH) a_nx2 = agp[(size_t)(ch + 2) * 32 * N_DIM];

    // fea fragments + E k-values for this wave's batch
    const ushort* tile = fb + (size_t)ch * (C_DIM * 32);
    const bf16x8 fa0 = *(const bf16x8*)(tile + l15 * 32 + quad * 8);
    const bf16x8 fa1 = *(const bf16x8*)(tile + (16 + l15) * 32 + quad * 8);
    float ekv[8];
    *(f32x4*)&ekv[0] = *(const f32x4*)(ekb + ch * 32 + quad * 8);
    *(f32x4*)&ekv[4] = *(const f32x4*)(ekb + ch * 32 + quad * 8 + 4);

    // adj fragment from this kh-group's LDS tile (shared by its 8 batches)
    float a2[8];
#pragma unroll
    for (int j = 0; j < 8; ++j) a2[j] = abuf[kh][(quad * 8 + j) * 33 + l15];

    // w = (2*adj) * min(Ek,Em) * rcp(Ek+Em)   (exact identity)
    uint4v wfu;
#pragma unroll
    for (int p = 0; p < 4; ++p) {
      const float e0 = ekv[2 * p];
      const float e1 = ekv[2 * p + 1];
      const float t0 = fminf(e0, Em);
      const float t1 = fminf(e1, Em);
      const float s0 = e0 + Em;
      const float s1 = e1 + Em;
      const float w0 = a2[2 * p] * t0 * __builtin_amdgcn_rcpf(s0);
      const float w1 = a2[2 * p + 1] * t1 * __builtin_amdgcn_rcpf(s1);
      // truncating bf16x2 pack: bytes [w0.b2, w0.b3, w1.b2, w1.b3]
      wfu[p] = __builtin_amdgcn_perm(__float_as_uint(w1), __float_as_uint(w0),
                                     0x07060302u);
    }
    const bf16x8 wf = __builtin_bit_cast(bf16x8, wfu);

    acc0 = __builtin_amdgcn_mfma_f32_16x16x32_bf16(fa0, wf, acc0, 0, 0, 0);
    acc1 = __builtin_amdgcn_mfma_f32_16x16x32_bf16(fa1, wf, acc1, 0, 0, 0);

    __syncthreads();   // all waves done reading their abuf tile for chunk ch
    if (ch + 1 < NCH) {
      abuf[kh][swaddr] = 2.0f * a_nxt;   // value loaded >=1 full chunk ago
      a_nxt = a_nx2;
    }
    __syncthreads();   // staged writes visible
  }

  // fused kh-reduce + epilogue (D layout: col=l15, row=quad*4+r)
  if (kh == 1) {
#pragma unroll
    for (int r = 0; r < 4; ++r) {
      red[b][(quad * 4 + r) * 16 + l15] = acc0[r];
      red[b][(16 + quad * 4 + r) * 16 + l15] = acc1[r];
    }
  }
  __syncthreads();
  if (kh == 0) {
#pragma unroll
    for (int r = 0; r < 4; ++r) {
      const int c0 = quad * 4 + r;
      const int c1 = c0 + 16;
      float s0 = acc0[r] + red[b][c0 * 16 + l15];
      float s1 = acc1[r] + red[b][c1 * 16 + l15];
      s0 *= para[(size_t)c0 * N_DIM + col];
      s1 *= para[(size_t)c1 * N_DIM + col];
      out[((size_t)(b * C_DIM + c0)) * N_DIM + col] = fmaxf(s0, 0.f);
      out[((size_t)(b * C_DIM + c1)) * N_DIM + col] = fmaxf(s1, 0.f);
    }
  }
}

extern "C" void kernel_launch(void* const* d_in, const int* in_sizes, int n_in,
                              void* d_out, int out_size, void* d_ws, size_t ws_size,
                              hipStream_t stream) {
  const float* x = (const float*)d_in[0];     // [8,32,64,64]
  const float* para = (const float*)d_in[1];  // [1,32,64,64]
  const float* adj = (const float*)d_in[2];   // [4096,4096]
  float* out = (float*)d_out;

  // ws: E (128 KB) | feabT (2 MB) -- total 2.25 MB
  float* E = (float*)d_ws;
  ushort* feabT = (ushort*)(E + (size_t)B_DIM * N_DIM);

  prep_e<<<dim3(B_DIM * N_DIM / 256), dim3(256), 0, stream>>>(x, E);
  prep_feab<<<dim3(B_DIM * C_DIM * (N_DIM / 16) / 256), dim3(256), 0, stream>>>(x, feabT);
  gcn_fused<<<dim3(N_DIM / 16), dim3(1024), 0, stream>>>(feabT, adj, E, para, out);
}